// Round 1
// baseline (1204.548 us; speedup 1.0000x reference)
//
#include <hip/hip_runtime.h>
#include <hip/hip_bf16.h>
#include <stdint.h>

#define T_TOK 4096
#define DM 1024
#define DF 4096
#define NE 8

typedef __attribute__((ext_vector_type(8))) short short8;
typedef __attribute__((ext_vector_type(4))) float f32x4;

__device__ __forceinline__ unsigned short f2bf(float f) {
    union { float f; unsigned u; } v; v.f = f;
    unsigned r = v.u + 0x7fffu + ((v.u >> 16) & 1u);   // RNE
    return (unsigned short)(r >> 16);
}

__device__ __forceinline__ void async_cp16(const void* g, void* l) {
    __builtin_amdgcn_global_load_lds(
        (const __attribute__((address_space(1))) unsigned*)g,
        (__attribute__((address_space(3))) unsigned*)l,
        16, 0, 0);
}

// ---------------- router: fp32 logits, top-2, softmax, scatter ----------------
__global__ __launch_bounds__(256) void k_router(
    const float* __restrict__ x, const float* __restrict__ rw,
    const float* __restrict__ rb, int* __restrict__ counts,
    int* __restrict__ listTok, float* __restrict__ listGate)
{
    int l  = threadIdx.x & 63;
    int wv = threadIdx.x >> 6;
    int t  = blockIdx.x * 4 + wv;
    const float* xr = x + (size_t)t * DM;
    float acc[NE];
#pragma unroll
    for (int e = 0; e < NE; ++e) acc[e] = 0.f;
#pragma unroll
    for (int i = 0; i < 16; ++i) {
        int d = i * 64 + l;                      // coalesced x reads
        float xv = xr[d];
        const float4* wp = (const float4*)(rw + (size_t)d * NE);
        float4 w0 = wp[0], w1 = wp[1];
        acc[0] += xv * w0.x; acc[1] += xv * w0.y; acc[2] += xv * w0.z; acc[3] += xv * w0.w;
        acc[4] += xv * w1.x; acc[5] += xv * w1.y; acc[6] += xv * w1.z; acc[7] += xv * w1.w;
    }
#pragma unroll
    for (int off = 32; off >= 1; off >>= 1)
#pragma unroll
        for (int e = 0; e < NE; ++e) acc[e] += __shfl_down(acc[e], off);
    if (l == 0) {
        float lg[NE];
#pragma unroll
        for (int e = 0; e < NE; ++e) lg[e] = acc[e] + rb[e];
        int i1 = 0; float s1 = lg[0];
#pragma unroll
        for (int e = 1; e < NE; ++e) if (lg[e] > s1) { s1 = lg[e]; i1 = e; }
        int i2 = -1; float s2 = -3.0e38f;
#pragma unroll
        for (int e = 0; e < NE; ++e) if (e != i1 && lg[e] > s2) { s2 = lg[e]; i2 = e; }
        float g1 = 1.f / (1.f + expf(s2 - s1));
        float g2 = 1.f - g1;
        int p1 = atomicAdd(&counts[i1], 1);
        listTok[i1 * T_TOK + p1] = t; listGate[i1 * T_TOK + p1] = g1;
        int p2 = atomicAdd(&counts[i2], 1);
        listTok[i2 * T_TOK + p2] = t; listGate[i2 * T_TOK + p2] = g2;
    }
}

// ---------------- 128-padded exclusive scan of counts ----------------
__global__ void k_offsets(const int* __restrict__ counts, int* __restrict__ offsets)
{
    int cum = 0;
    for (int e = 0; e < NE; ++e) { offsets[e] = cum; cum += (counts[e] + 127) & ~127; }
    offsets[NE] = cum;
}

// ---------------- x fp32 -> bf16 ----------------
__global__ __launch_bounds__(256) void k_convx(const float* __restrict__ src,
                                               unsigned short* __restrict__ dst)
{
    size_t i = ((size_t)blockIdx.x * 256 + threadIdx.x) * 4;
    float4 v = *(const float4*)(src + i);
    ushort4 o; o.x = f2bf(v.x); o.y = f2bf(v.y); o.z = f2bf(v.z); o.w = f2bf(v.w);
    *(ushort4*)(dst + i) = o;
}

// ---------------- per-expert transpose + fp32->bf16: [E][R][C] -> [E][C][R] ----------------
__global__ __launch_bounds__(256) void k_convT(const float* __restrict__ src,
                                               unsigned short* __restrict__ dst,
                                               int R, int C)
{
    __shared__ float tile[64][65];
    int e  = blockIdx.z;
    int c0 = blockIdx.x * 64, r0 = blockIdx.y * 64;
    const float* s      = src + (size_t)e * R * C;
    unsigned short* d   = dst + (size_t)e * R * C;
#pragma unroll
    for (int i = 0; i < 16; ++i) {
        int idx = i * 256 + threadIdx.x;
        int rr = idx >> 6, cc = idx & 63;
        tile[rr][cc] = s[(size_t)(r0 + rr) * C + (c0 + cc)];
    }
    __syncthreads();
#pragma unroll
    for (int i = 0; i < 16; ++i) {
        int idx = i * 256 + threadIdx.x;
        int cr = idx >> 6, rc = idx & 63;
        d[(size_t)(c0 + cr) * R + (r0 + rc)] = f2bf(tile[rc][cr]);
    }
}

// ---------------- GEMM1: H = gelu(gather(X) @ W1 + b1), bf16 MFMA ----------------
// A: gathered xb rows [cnt x 1024]; B: w1t [e][f][d] (K-contiguous); out H bf16 [pad-rows][4096]
__global__ __launch_bounds__(256) void k_ffn1(
    const unsigned short* __restrict__ xb, const unsigned short* __restrict__ w1t,
    const float* __restrict__ b1, const int* __restrict__ listTok,
    const int* __restrict__ counts, const int* __restrict__ offsets,
    unsigned short* __restrict__ H)
{
    __shared__ __align__(16) unsigned short lsA[128 * 32];
    __shared__ __align__(16) unsigned short lsB[128 * 32];
    int e   = blockIdx.x >> 5;
    int m0  = (blockIdx.x & 31) << 7;
    int cnt = counts[e];
    if (m0 >= cnt) return;
    int n0    = blockIdx.y << 7;
    int hbase = offsets[e];
    int tid = threadIdx.x, wv = tid >> 6, l = tid & 63;
    int wm = wv & 1, wn = wv >> 1;

    int row0 = wv * 32 + (l >> 2);
    int row1 = row0 + 16;
    int kp   = (l & 3) * 8;
    int r0 = m0 + row0; if (r0 > cnt - 1) r0 = cnt - 1;   // clamp gather for pad rows
    int r1 = m0 + row1; if (r1 > cnt - 1) r1 = cnt - 1;
    const int* lt = listTok + e * T_TOK;
    const unsigned short* gA0 = xb + (size_t)lt[r0] * DM + kp;
    const unsigned short* gA1 = xb + (size_t)lt[r1] * DM + kp;
    const unsigned short* wb  = w1t + (size_t)e * DF * DM;
    const unsigned short* gB0 = wb + (size_t)(n0 + row0) * DM + kp;
    const unsigned short* gB1 = wb + (size_t)(n0 + row1) * DM + kp;
    unsigned short* lA0 = &lsA[(wv * 32) * 32];
    unsigned short* lA1 = &lsA[(wv * 32 + 16) * 32];
    unsigned short* lB0 = &lsB[(wv * 32) * 32];
    unsigned short* lB1 = &lsB[(wv * 32 + 16) * 32];

    f32x4 acc[4][4];
#pragma unroll
    for (int i = 0; i < 4; ++i)
#pragma unroll
        for (int j = 0; j < 4; ++j) acc[i][j] = (f32x4)(0.f);

    int aoff = (wm * 64 + (l & 15)) * 32 + (l >> 4) * 8;
    int boff = (wn * 64 + (l & 15)) * 32 + (l >> 4) * 8;

    for (int k0 = 0; k0 < DM; k0 += 32) {
        async_cp16(gA0 + k0, lA0);
        async_cp16(gA1 + k0, lA1);
        async_cp16(gB0 + k0, lB0);
        async_cp16(gB1 + k0, lB1);
        __syncthreads();
        short8 aF[4], bF[4];
#pragma unroll
        for (int mi = 0; mi < 4; ++mi) aF[mi] = *(const short8*)&lsA[aoff + mi * 16 * 32];
#pragma unroll
        for (int ni = 0; ni < 4; ++ni) bF[ni] = *(const short8*)&lsB[boff + ni * 16 * 32];
#pragma unroll
        for (int mi = 0; mi < 4; ++mi)
#pragma unroll
            for (int ni = 0; ni < 4; ++ni)
                acc[mi][ni] = __builtin_amdgcn_mfma_f32_16x16x32_bf16(aF[mi], bF[ni], acc[mi][ni], 0, 0, 0);
        __syncthreads();
    }

    int q = l >> 4, cn = l & 15;
#pragma unroll
    for (int mi = 0; mi < 4; ++mi) {
#pragma unroll
        for (int ni = 0; ni < 4; ++ni) {
            int n = n0 + wn * 64 + ni * 16 + cn;
            float bias = b1[e * DF + n];
#pragma unroll
            for (int rg = 0; rg < 4; ++rg) {
                int m = wm * 64 + mi * 16 + q * 4 + rg;
                float v = acc[mi][ni][rg] + bias;
                v = 0.5f * v * (1.f + erff(v * 0.70710678118f));   // exact GELU
                H[(size_t)(hbase + m0 + m) * DF + n] = f2bf(v);
            }
        }
    }
}

// ---------------- GEMM2: out[tok] += gate * (H @ W2 + b2), atomic scatter ----------------
__global__ __launch_bounds__(256) void k_ffn2(
    const unsigned short* __restrict__ H, const unsigned short* __restrict__ w2t,
    const float* __restrict__ b2, const int* __restrict__ listTok,
    const float* __restrict__ listGate, const int* __restrict__ counts,
    const int* __restrict__ offsets, float* __restrict__ out)
{
    __shared__ __align__(16) unsigned short lsA[128 * 32];
    __shared__ __align__(16) unsigned short lsB[128 * 32];
    int e   = blockIdx.x >> 5;
    int m0  = (blockIdx.x & 31) << 7;
    int cnt = counts[e];
    if (m0 >= cnt) return;
    int n0    = blockIdx.y << 7;
    int hbase = offsets[e];
    int tid = threadIdx.x, wv = tid >> 6, l = tid & 63;
    int wm = wv & 1, wn = wv >> 1;

    int row0 = wv * 32 + (l >> 2);
    int row1 = row0 + 16;
    int kp   = (l & 3) * 8;
    const unsigned short* gA0 = H + (size_t)(hbase + m0 + row0) * DF + kp;
    const unsigned short* gA1 = H + (size_t)(hbase + m0 + row1) * DF + kp;
    const unsigned short* wb  = w2t + (size_t)e * DM * DF;
    const unsigned short* gB0 = wb + (size_t)(n0 + row0) * DF + kp;
    const unsigned short* gB1 = wb + (size_t)(n0 + row1) * DF + kp;
    unsigned short* lA0 = &lsA[(wv * 32) * 32];
    unsigned short* lA1 = &lsA[(wv * 32 + 16) * 32];
    unsigned short* lB0 = &lsB[(wv * 32) * 32];
    unsigned short* lB1 = &lsB[(wv * 32 + 16) * 32];

    f32x4 acc[4][4];
#pragma unroll
    for (int i = 0; i < 4; ++i)
#pragma unroll
        for (int j = 0; j < 4; ++j) acc[i][j] = (f32x4)(0.f);

    int aoff = (wm * 64 + (l & 15)) * 32 + (l >> 4) * 8;
    int boff = (wn * 64 + (l & 15)) * 32 + (l >> 4) * 8;

    for (int k0 = 0; k0 < DF; k0 += 32) {
        async_cp16(gA0 + k0, lA0);
        async_cp16(gA1 + k0, lA1);
        async_cp16(gB0 + k0, lB0);
        async_cp16(gB1 + k0, lB1);
        __syncthreads();
        short8 aF[4], bF[4];
#pragma unroll
        for (int mi = 0; mi < 4; ++mi) aF[mi] = *(const short8*)&lsA[aoff + mi * 16 * 32];
#pragma unroll
        for (int ni = 0; ni < 4; ++ni) bF[ni] = *(const short8*)&lsB[boff + ni * 16 * 32];
#pragma unroll
        for (int mi = 0; mi < 4; ++mi)
#pragma unroll
            for (int ni = 0; ni < 4; ++ni)
                acc[mi][ni] = __builtin_amdgcn_mfma_f32_16x16x32_bf16(aF[mi], bF[ni], acc[mi][ni], 0, 0, 0);
        __syncthreads();
    }

    int q = l >> 4, cn = l & 15;
    const int* lt    = listTok  + e * T_TOK;
    const float* lgt = listGate + e * T_TOK;
#pragma unroll
    for (int mi = 0; mi < 4; ++mi) {
#pragma unroll
        for (int rg = 0; rg < 4; ++rg) {
            int m = wm * 64 + mi * 16 + q * 4 + rg;
            int r = m0 + m;
            if (r < cnt) {
                int tok = lt[r];
                float g = lgt[r];
                float* orow = out + (size_t)tok * DM;
#pragma unroll
                for (int ni = 0; ni < 4; ++ni) {
                    int n = n0 + wn * 64 + ni * 16 + cn;
                    float v = acc[mi][ni][rg] + b2[e * DM + n];
                    atomicAdd(&orow[n], g * v);
                }
            }
        }
    }
}

extern "C" void kernel_launch(void* const* d_in, const int* in_sizes, int n_in,
                              void* d_out, int out_size, void* d_ws, size_t ws_size,
                              hipStream_t stream)
{
    const float* x  = (const float*)d_in[0];
    const float* rw = (const float*)d_in[1];
    const float* rb = (const float*)d_in[2];
    const float* w1 = (const float*)d_in[3];
    const float* b1 = (const float*)d_in[4];
    const float* w2 = (const float*)d_in[5];
    const float* b2 = (const float*)d_in[6];
    float* out = (float*)d_out;

    char* ws = (char*)d_ws;
    // workspace layout (~208 MB total)
    int*            counts   = (int*)(ws + 0);                    // 32 B
    int*            offsets  = (int*)(ws + 128);                  // 36 B
    int*            listTok  = (int*)(ws + 512);                  // 128 KiB
    float*          listGate = (float*)(ws + 512 + 131072);       // 128 KiB
    unsigned short* xb       = (unsigned short*)(ws + 262656);    // 8 MiB
    unsigned short* w1t      = (unsigned short*)(ws + 8651264);   // 64 MiB  [E][F][D]
    unsigned short* w2t      = (unsigned short*)(ws + 75760128);  // 64 MiB  [E][D][F]
    unsigned short* Hbuf     = (unsigned short*)(ws + 142868992); // 72 MiB  [9216][4096]

    hipMemsetAsync(counts, 0, 32, stream);
    hipMemsetAsync(d_out, 0, (size_t)out_size * sizeof(float), stream);

    k_router <<<T_TOK / 4, 256, 0, stream>>>(x, rw, rb, counts, listTok, listGate);
    k_offsets<<<1, 1, 0, stream>>>(counts, offsets);
    k_convx  <<<(T_TOK * DM) / 1024, 256, 0, stream>>>(x, xb);
    k_convT  <<<dim3(DF / 64, DM / 64, NE), 256, 0, stream>>>(w1, w1t, DM, DF);
    k_convT  <<<dim3(DM / 64, DF / 64, NE), 256, 0, stream>>>(w2, w2t, DF, DM);
    k_ffn1   <<<dim3(NE * 32, DF / 128), 256, 0, stream>>>(xb, w1t, b1, listTok, counts, offsets, Hbuf);
    k_ffn2   <<<dim3(NE * 32, DM / 128), 256, 0, stream>>>(Hbuf, w2t, b2, listTok, listGate, counts, offsets, out);
}

// Round 4
// 698.450 us; speedup vs baseline: 1.7246x; 1.7246x over previous
//
#include <hip/hip_runtime.h>
#include <hip/hip_bf16.h>
#include <stdint.h>

#define T_TOK 4096
#define DM 1024
#define DF 4096
#define NE 8
#define PADROWS 9216   // max padded rows: 8192 + 8*127 rounded up

typedef __attribute__((ext_vector_type(8))) short short8;
typedef __attribute__((ext_vector_type(8))) unsigned short ushort8_t;  // 8 ushorts = 16 B
typedef __attribute__((ext_vector_type(4))) float f32x4;

__device__ __forceinline__ unsigned short f2bf(float f) {
    union { float f; unsigned u; } v; v.f = f;
    unsigned r = v.u + 0x7fffu + ((v.u >> 16) & 1u);   // RNE
    return (unsigned short)(r >> 16);
}

__device__ __forceinline__ void async_cp16(const void* g, void* l) {
    __builtin_amdgcn_global_load_lds(
        (const __attribute__((address_space(1))) unsigned*)g,
        (__attribute__((address_space(3))) unsigned*)l,
        16, 0, 0);
}

// ---------------- router: fp32 logits, top-2, softmax, scatter ----------------
__global__ __launch_bounds__(256) void k_router(
    const float* __restrict__ x, const float* __restrict__ rw,
    const float* __restrict__ rb, int* __restrict__ counts,
    int* __restrict__ listTok, float* __restrict__ listGate)
{
    int l  = threadIdx.x & 63;
    int wv = threadIdx.x >> 6;
    int t  = blockIdx.x * 4 + wv;
    const float* xr = x + (size_t)t * DM;
    float acc[NE];
#pragma unroll
    for (int e = 0; e < NE; ++e) acc[e] = 0.f;
#pragma unroll
    for (int i = 0; i < 16; ++i) {
        int d = i * 64 + l;
        float xv = xr[d];
        const float4* wp = (const float4*)(rw + (size_t)d * NE);
        float4 w0 = wp[0], w1 = wp[1];
        acc[0] += xv * w0.x; acc[1] += xv * w0.y; acc[2] += xv * w0.z; acc[3] += xv * w0.w;
        acc[4] += xv * w1.x; acc[5] += xv * w1.y; acc[6] += xv * w1.z; acc[7] += xv * w1.w;
    }
#pragma unroll
    for (int off = 32; off >= 1; off >>= 1)
#pragma unroll
        for (int e = 0; e < NE; ++e) acc[e] += __shfl_down(acc[e], off);
    if (l == 0) {
        float lg[NE];
#pragma unroll
        for (int e = 0; e < NE; ++e) lg[e] = acc[e] + rb[e];
        int i1 = 0; float s1 = lg[0];
#pragma unroll
        for (int e = 1; e < NE; ++e) if (lg[e] > s1) { s1 = lg[e]; i1 = e; }
        int i2 = -1; float s2 = -3.0e38f;
#pragma unroll
        for (int e = 0; e < NE; ++e) if (e != i1 && lg[e] > s2) { s2 = lg[e]; i2 = e; }
        float g1 = 1.f / (1.f + expf(s2 - s1));
        float g2 = 1.f - g1;
        int p1 = atomicAdd(&counts[i1], 1);
        listTok[i1 * T_TOK + p1] = t; listGate[i1 * T_TOK + p1] = g1;
        int p2 = atomicAdd(&counts[i2], 1);
        listTok[i2 * T_TOK + p2] = t; listGate[i2 * T_TOK + p2] = g2;
    }
}

// ---------------- 128-padded exclusive scan of counts ----------------
__global__ void k_offsets(const int* __restrict__ counts, int* __restrict__ offsets)
{
    int cum = 0;
    for (int e = 0; e < NE; ++e) { offsets[e] = cum; cum += (counts[e] + 127) & ~127; }
    offsets[NE] = cum;
}

// ---------------- weight pack: fp32 [E][K][N] -> bf16 swizzled [E][K/64][N][64] ----------------
// element (e, k, n) -> dst[e][(k>>6)*N + n]*64 + ((g ^ (n&7))*8 + (k&7)], g=(k&63)>>3
__global__ __launch_bounds__(256) void k_packw(const float* __restrict__ src,
                                               unsigned short* __restrict__ dst,
                                               int K, int N)
{
    __shared__ float tile[64][65];
    int e  = blockIdx.z;
    int n0 = blockIdx.x * 64;
    int k0 = blockIdx.y * 64;
    const float* s    = src + (size_t)e * K * N;
    unsigned short* d = dst + (size_t)e * K * N;
    int tid = threadIdx.x;
#pragma unroll
    for (int i = 0; i < 4; ++i) {
        int u  = i * 256 + tid;
        int kk = u >> 4;
        int nn = (u & 15) * 4;
        float4 v = *(const float4*)(s + (size_t)(k0 + kk) * N + n0 + nn);
        tile[kk][nn] = v.x; tile[kk][nn + 1] = v.y; tile[kk][nn + 2] = v.z; tile[kk][nn + 3] = v.w;
    }
    __syncthreads();
#pragma unroll
    for (int i = 0; i < 4; ++i) {
        int u  = i * 256 + tid;
        int nn = u >> 4;
        int g  = (u >> 1) & 7;
        int h  = (u & 1) * 4;
        int kc = g * 8 + h;
        int n  = n0 + nn;
        ushort4 o;
        o.x = f2bf(tile[kc + 0][nn]); o.y = f2bf(tile[kc + 1][nn]);
        o.z = f2bf(tile[kc + 2][nn]); o.w = f2bf(tile[kc + 3][nn]);
        int gp = g ^ (n & 7);
        size_t off = ((size_t)(k0 >> 6) * N + n) * 64 + gp * 8 + h;
        *(ushort4*)(d + off) = o;
    }
}

// ---------------- A pack: gather tokens + fp32->bf16 into swizzled [16][PADROWS][64] ----------------
__global__ __launch_bounds__(256) void k_packa(
    const float* __restrict__ x, const int* __restrict__ listTok,
    const int* __restrict__ counts, const int* __restrict__ offsets,
    unsigned short* __restrict__ ap)
{
    int r0  = blockIdx.x * 64;
    int kt  = blockIdx.y;
    int tid = threadIdx.x;
    __shared__ int toks[64];
    if (tid < 64) {
        int r = r0 + tid;
        int tok = 0;
        int total = offsets[NE];
        if (r < total) {
            int e = 0;
#pragma unroll
            for (int j = 1; j < NE; ++j) if (r >= offsets[j]) e = j;
            int local = r - offsets[e];
            int c = counts[e];
            if (local >= c) local = c - 1;
            if (local < 0) local = 0;
            tok = listTok[e * T_TOK + local];
        }
        toks[tid] = tok;
    }
    __syncthreads();
#pragma unroll
    for (int i = 0; i < 4; ++i) {
        int u  = i * 256 + tid;
        int rl = u >> 4;
        int g  = (u >> 1) & 7;
        int h  = (u & 1) * 4;
        int tok = toks[rl];
        float4 v = *(const float4*)(x + (size_t)tok * DM + kt * 64 + g * 8 + h);
        ushort4 o; o.x = f2bf(v.x); o.y = f2bf(v.y); o.z = f2bf(v.z); o.w = f2bf(v.w);
        int row = r0 + rl;
        int gp  = g ^ (row & 7);
        size_t off = ((size_t)kt * PADROWS + row) * 64 + gp * 8 + h;
        *(ushort4*)(ap + off) = o;
    }
}

// ---------------- GEMM1: Hp = gelu(Apack @ W1p + b1), packed in / packed out ----------------
__global__ __launch_bounds__(256) void k_ffn1(
    const unsigned short* __restrict__ ap, const unsigned short* __restrict__ w1p,
    const float* __restrict__ b1, const int* __restrict__ counts,
    const int* __restrict__ offsets, unsigned short* __restrict__ Hp)
{
    __shared__ __align__(16) unsigned short lsA[128 * 64];   // 16 KB
    __shared__ __align__(16) unsigned short lsB[128 * 64];   // 16 KB
    int i  = blockIdx.x;
    int l0 = ((i & 7) << 10) + (i >> 3);     // XCD-grouping swizzle, 8192 blocks
    int xx = l0 & 255, y = l0 >> 8;          // y = n-tile 0..31
    int e = xx >> 5, mt = xx & 31;
    int cnt = counts[e];
    int m0  = mt << 7;
    if (m0 >= cnt) return;
    int hbase = offsets[e];
    int n0    = y << 7;
    int tid = threadIdx.x, wv = tid >> 6, l = tid & 63;
    int wm = wv & 1, wn = wv >> 1;

    const unsigned short* srcA = ap + ((size_t)hbase + m0) * 64;
    const unsigned short* srcB = w1p + (size_t)e * DM * DF;

    f32x4 acc[4][4];
#pragma unroll
    for (int a = 0; a < 4; ++a)
#pragma unroll
        for (int b = 0; b < 4; ++b) acc[a][b] = (f32x4)(0.f);

    for (int kt = 0; kt < 16; ++kt) {
        const unsigned short* gA = srcA + (size_t)kt * PADROWS * 64;
        const unsigned short* gB = srcB + ((size_t)kt * DF + n0) * 64;
#pragma unroll
        for (int j = 0; j < 4; ++j) {
            int c = (wv * 4 + j) * 512;   // 1 KB chunks (elements)
            async_cp16(gA + c + l * 8, lsA + c);
            async_cp16(gB + c + l * 8, lsB + c);
        }
        __syncthreads();
#pragma unroll
        for (int ks = 0; ks < 2; ++ks) {
            short8 aF[4], bF[4];
#pragma unroll
            for (int mi = 0; mi < 4; ++mi) {
                int row = wm * 64 + mi * 16 + (l & 15);
                int g   = ks * 4 + (l >> 4);
                aF[mi] = *(const short8*)&lsA[row * 64 + ((g ^ (row & 7)) << 3)];
            }
#pragma unroll
            for (int ni = 0; ni < 4; ++ni) {
                int row = wn * 64 + ni * 16 + (l & 15);
                int g   = ks * 4 + (l >> 4);
                bF[ni] = *(const short8*)&lsB[row * 64 + ((g ^ (row & 7)) << 3)];
            }
#pragma unroll
            for (int mi = 0; mi < 4; ++mi)
#pragma unroll
                for (int ni = 0; ni < 4; ++ni)
                    acc[mi][ni] = __builtin_amdgcn_mfma_f32_16x16x32_bf16(aF[mi], bF[ni], acc[mi][ni], 0, 0, 0);
        }
        __syncthreads();
    }

    // epilogue: bias + exact GELU -> LDS packed image -> vectorized store
    int q = l >> 4, cn = l & 15;
#pragma unroll
    for (int mi = 0; mi < 4; ++mi) {
#pragma unroll
        for (int ni = 0; ni < 4; ++ni) {
            int nloc = wn * 64 + ni * 16 + cn;             // 0..127
            float bias = b1[e * DF + n0 + nloc];
            unsigned short* base = (nloc & 64) ? lsB : lsA;
            int kc = nloc & 63, g = kc >> 3;
#pragma unroll
            for (int rg = 0; rg < 4; ++rg) {
                int m = wm * 64 + mi * 16 + q * 4 + rg;
                float v = acc[mi][ni][rg] + bias;
                v = 0.5f * v * (1.f + erff(v * 0.70710678118f));
                int gp = g ^ (m & 7);
                base[m * 64 + gp * 8 + (kc & 7)] = f2bf(v);
            }
        }
    }
    __syncthreads();
    {
        int c = tid >> 7;            // chunk 0/1
        int r = tid & 127;           // row
        const unsigned short* s = (c ? lsB : lsA) + r * 64;
        unsigned short* dst = Hp + (((size_t)(n0 >> 6) + c) * PADROWS + hbase + m0 + r) * 64;
        // FIX (round 4): ushort8_t is 8 elements (16 B); full 64-element row
        // needs 8 stores at stride 8, not 4 at stride 16 (which left gaps of poison).
#pragma unroll
        for (int j = 0; j < 8; ++j)
            *(ushort8_t*)(dst + j * 8) = *(const ushort8_t*)(s + j * 8);
    }
}

// ---------------- GEMM2: out[tok] += gate * (Hp @ W2p + b2), atomic scatter ----------------
__global__ __launch_bounds__(256) void k_ffn2(
    const unsigned short* __restrict__ Hp, const unsigned short* __restrict__ w2p,
    const float* __restrict__ b2, const int* __restrict__ listTok,
    const float* __restrict__ listGate, const int* __restrict__ counts,
    const int* __restrict__ offsets, float* __restrict__ out)
{
    __shared__ __align__(16) unsigned short lsA[128 * 64];
    __shared__ __align__(16) unsigned short lsB[128 * 64];
    int i  = blockIdx.x;
    int l0 = ((i & 7) << 8) + (i >> 3);      // 2048 blocks, B/8=256
    int xx = l0 & 255, y = l0 >> 8;          // y = n-tile 0..7
    int e = xx >> 5, mt = xx & 31;
    int cnt = counts[e];
    int m0  = mt << 7;
    if (m0 >= cnt) return;
    int hbase = offsets[e];
    int n0    = y << 7;
    int tid = threadIdx.x, wv = tid >> 6, l = tid & 63;
    int wm = wv & 1, wn = wv >> 1;

    const unsigned short* srcA = Hp + ((size_t)hbase + m0) * 64;
    const unsigned short* srcB = w2p + (size_t)e * DF * DM;

    f32x4 acc[4][4];
#pragma unroll
    for (int a = 0; a < 4; ++a)
#pragma unroll
        for (int b = 0; b < 4; ++b) acc[a][b] = (f32x4)(0.f);

    for (int kt = 0; kt < 64; ++kt) {
        const unsigned short* gA = srcA + (size_t)kt * PADROWS * 64;
        const unsigned short* gB = srcB + ((size_t)kt * DM + n0) * 64;
#pragma unroll
        for (int j = 0; j < 4; ++j) {
            int c = (wv * 4 + j) * 512;
            async_cp16(gA + c + l * 8, lsA + c);
            async_cp16(gB + c + l * 8, lsB + c);
        }
        __syncthreads();
#pragma unroll
        for (int ks = 0; ks < 2; ++ks) {
            short8 aF[4], bF[4];
#pragma unroll
            for (int mi = 0; mi < 4; ++mi) {
                int row = wm * 64 + mi * 16 + (l & 15);
                int g   = ks * 4 + (l >> 4);
                aF[mi] = *(const short8*)&lsA[row * 64 + ((g ^ (row & 7)) << 3)];
            }
#pragma unroll
            for (int ni = 0; ni < 4; ++ni) {
                int row = wn * 64 + ni * 16 + (l & 15);
                int g   = ks * 4 + (l >> 4);
                bF[ni] = *(const short8*)&lsB[row * 64 + ((g ^ (row & 7)) << 3)];
            }
#pragma unroll
            for (int mi = 0; mi < 4; ++mi)
#pragma unroll
                for (int ni = 0; ni < 4; ++ni)
                    acc[mi][ni] = __builtin_amdgcn_mfma_f32_16x16x32_bf16(aF[mi], bF[ni], acc[mi][ni], 0, 0, 0);
        }
        __syncthreads();
    }

    int q = l >> 4, cn = l & 15;
    const int*   lt  = listTok  + e * T_TOK;
    const float* lgt = listGate + e * T_TOK;
#pragma unroll
    for (int mi = 0; mi < 4; ++mi) {
#pragma unroll
        for (int rg = 0; rg < 4; ++rg) {
            int m = wm * 64 + mi * 16 + q * 4 + rg;
            int r = m0 + m;
            if (r < cnt) {
                int tok = lt[r];
                float ggt = lgt[r];
                float* orow = out + (size_t)tok * DM;
#pragma unroll
                for (int ni = 0; ni < 4; ++ni) {
                    int n = n0 + wn * 64 + ni * 16 + cn;
                    float v = acc[mi][ni][rg] + b2[e * DM + n];
                    atomicAdd(&orow[n], ggt * v);
                }
            }
        }
    }
}

extern "C" void kernel_launch(void* const* d_in, const int* in_sizes, int n_in,
                              void* d_out, int out_size, void* d_ws, size_t ws_size,
                              hipStream_t stream)
{
    const float* x  = (const float*)d_in[0];
    const float* rw = (const float*)d_in[1];
    const float* rb = (const float*)d_in[2];
    const float* w1 = (const float*)d_in[3];
    const float* b1 = (const float*)d_in[4];
    const float* w2 = (const float*)d_in[5];
    const float* b2 = (const float*)d_in[6];
    float* out = (float*)d_out;

    char* ws = (char*)d_ws;
    // workspace layout — max footprint 161,743,360 B (< round-1-proven 218 MB).
    // w2p ALIASES apack+w1p: written by the second k_packw, which runs AFTER
    // k_ffn1 has finished consuming apack/w1p (same-stream ordering).
    int*            counts   = (int*)(ws + 0);
    int*            offsets  = (int*)(ws + 128);
    int*            listTok  = (int*)(ws + 512);
    float*          listGate = (float*)(ws + 512 + 131072);
    unsigned short* apack    = (unsigned short*)(ws + 262656);    // 18.9 MB [16][9216][64]
    unsigned short* w2p      = (unsigned short*)(ws + 262656);    // 64 MB (alias, used after ffn1)
    unsigned short* w1p      = (unsigned short*)(ws + 19137024);  // 64 MB
    unsigned short* Hp       = (unsigned short*)(ws + 86245888);  // 75.5 MB [64][9216][64]

    hipMemsetAsync(counts, 0, 32, stream);
    hipMemsetAsync(d_out, 0, (size_t)out_size * sizeof(float), stream);

    k_router <<<T_TOK / 4, 256, 0, stream>>>(x, rw, rb, counts, listTok, listGate);
    k_offsets<<<1, 1, 0, stream>>>(counts, offsets);
    k_packw  <<<dim3(DF / 64, DM / 64, NE), 256, 0, stream>>>(w1, w1p, DM, DF);
    k_packa  <<<dim3(PADROWS / 64, 16), 256, 0, stream>>>(x, listTok, counts, offsets, apack);
    k_ffn1   <<<NE * 32 * 32, 256, 0, stream>>>(apack, w1p, b1, counts, offsets, Hp);
    k_packw  <<<dim3(DM / 64, DF / 64, NE), 256, 0, stream>>>(w2, w2p, DF, DM);
    k_ffn2   <<<NE * 32 * 8, 256, 0, stream>>>(Hp, w2p, b2, listTok, listGate, counts, offsets, out);
}